// Round 3
// baseline (575.443 us; speedup 1.0000x reference)
//
#include <hip/hip_runtime.h>
#include <cstdint>
#include <cstddef>

#define DF 128      // feature dim
#define HATT 64     // attention hidden dim

static inline int divup(int a, int b) { return (a + b - 1) / b; }

// ---------------- graph prep ----------------

__global__ __launch_bounds__(256) void hist_kernel(const int* __restrict__ row,
                                                   int* __restrict__ cnt, int E) {
    int i = blockIdx.x * blockDim.x + threadIdx.x;
    int stride = gridDim.x * blockDim.x;
    for (; i < E; i += stride) atomicAdd(&cnt[row[i]], 1);
}

// single block, 1024 threads: exclusive scan of cnt -> row_ptr, copy to cur
__global__ __launch_bounds__(1024) void scan_kernel(const int* __restrict__ cnt,
                                                    int* __restrict__ row_ptr,
                                                    int* __restrict__ cur, int n) {
    __shared__ int sums[1024];
    int t = threadIdx.x;
    int chunk = (n + 1023) >> 10;
    int start = t * chunk;
    int s = 0;
    for (int j = 0; j < chunk; ++j) {
        int idx = start + j;
        if (idx < n) s += cnt[idx];
    }
    sums[t] = s;
    __syncthreads();
    for (int off = 1; off < 1024; off <<= 1) {
        int v = (t >= off) ? sums[t - off] : 0;
        __syncthreads();
        sums[t] += v;
        __syncthreads();
    }
    int run = sums[t] - s;  // exclusive prefix
    for (int j = 0; j < chunk; ++j) {
        int idx = start + j;
        if (idx < n) {
            row_ptr[idx] = run;
            cur[idx] = run;
            run += cnt[idx];
        }
    }
    if (t == 1023) row_ptr[n] = sums[1023];
}

__global__ __launch_bounds__(256) void scatter_kernel(const int* __restrict__ row,
                                                      const int* __restrict__ col,
                                                      int* __restrict__ cur,
                                                      int* __restrict__ col_s, int E) {
    int i = blockIdx.x * blockDim.x + threadIdx.x;
    int stride = gridDim.x * blockDim.x;
    for (; i < E; i += stride) {
        int r = row[i];
        int p = atomicAdd(&cur[r], 1);
        col_s[p] = col[i];
    }
}

// ---------------- split x into two 64-feature halves + squared norms ----------------

__global__ __launch_bounds__(256) void split_x_kernel(const float* __restrict__ x,
                                                      float* __restrict__ xA,
                                                      float* __restrict__ xB,
                                                      float* __restrict__ sqn, int n) {
    int wid = (blockIdx.x * blockDim.x + threadIdx.x) >> 6;
    int lane = threadIdx.x & 63;
    if (wid >= n) return;
    float v0 = x[(size_t)wid * DF + lane];
    float v1 = x[(size_t)wid * DF + 64 + lane];
    xA[(size_t)wid * 64 + lane] = v0;
    xB[(size_t)wid * 64 + lane] = v1;
    float s = v0 * v0 + v1 * v1;
    for (int off = 32; off; off >>= 1) s += __shfl_xor(s, off);
    if (lane == 0) sqn[wid] = s;
}

// ---------------- edge weights, 2-phase over feature halves ----------------
// pass A: partial dot over half-table tA (2.56 MB, L2-resident) -> dpart[E]
__global__ __launch_bounds__(256) void edgewA_kernel(const float* __restrict__ tA,
                                                     const int* __restrict__ col_s,
                                                     const int* __restrict__ row_ptr,
                                                     float* __restrict__ dpart, int n) {
    int wid = (blockIdx.x * blockDim.x + threadIdx.x) >> 6;
    int lane = threadIdx.x & 63;
    if (wid >= n) return;
    int sub = lane & 15;   // 16 lanes per edge
    int g = lane >> 4;     // 4 edge groups per wave
    int s = row_ptr[wid], e = row_ptr[wid + 1];
    float4 a = ((const float4*)(tA + (size_t)wid * 64))[sub];
    for (int p = s + g; p < e; p += 4) {
        int c = col_s[p];
        float4 b = ((const float4*)(tA + (size_t)c * 64))[sub];
        float d = a.x * b.x + a.y * b.y + a.z * b.z + a.w * b.w;
        for (int off = 8; off; off >>= 1) d += __shfl_xor(d, off);
        if (sub == 0) dpart[p] = d;
    }
}

// pass B: finish dot with half-table tB, emit weights, fused degree -> dis
// METRIC: 0 = both (wA=cos->disA, wB=euc->disB), 1 = cos only, 2 = euc only
template <int METRIC>
__global__ __launch_bounds__(256) void edgewB_kernel(const float* __restrict__ tB,
                                                     const float* __restrict__ sqn,
                                                     const int* __restrict__ col_s,
                                                     const int* __restrict__ row_ptr,
                                                     const float* __restrict__ dpart,
                                                     float* __restrict__ wA,
                                                     float* __restrict__ wB,
                                                     float* __restrict__ disA,
                                                     float* __restrict__ disB, int n) {
    int wid = (blockIdx.x * blockDim.x + threadIdx.x) >> 6;
    int lane = threadIdx.x & 63;
    if (wid >= n) return;
    int sub = lane & 15;
    int g = lane >> 4;
    int s = row_ptr[wid], e = row_ptr[wid + 1];
    float4 a = ((const float4*)(tB + (size_t)wid * 64))[sub];
    float na = sqn[wid];
    float accA = 0.f, accB = 0.f;
    for (int p = s + g; p < e; p += 4) {
        int c = col_s[p];
        float4 b = ((const float4*)(tB + (size_t)c * 64))[sub];
        float d = a.x * b.x + a.y * b.y + a.z * b.z + a.w * b.w;
        for (int off = 8; off; off >>= 1) d += __shfl_xor(d, off);
        if (sub == 0) {
            d += dpart[p];
            float nb = sqn[c];
            if (METRIC != 2) {
                float cw = d / fmaxf(sqrtf(na * nb), 1e-8f);
                wA[p] = cw;
                accA += cw;
            }
            if (METRIC == 0) {
                float ew = sqrtf(fmaxf(na + nb - 2.f * d, 0.f) + 1e-12f);
                wB[p] = ew;
                accB += ew;
            }
            if (METRIC == 2) {
                float ew = sqrtf(fmaxf(na + nb - 2.f * d, 0.f) + 1e-12f);
                wA[p] = ew;
                accA += ew;
            }
        }
    }
    // group sums live on lanes 0,16,32,48; fold them into lane 0
    accA += __shfl_xor(accA, 32);
    accA += __shfl_xor(accA, 16);
    if (METRIC == 0) {
        accB += __shfl_xor(accB, 32);
        accB += __shfl_xor(accB, 16);
    }
    if (lane == 0) {
        float dA = 1.f + accA;
        disA[wid] = (dA > 0.f) ? rsqrtf(fmaxf(dA, 1e-12f)) : 0.f;
        if (METRIC == 0) {
            float dB = 1.f + accB;
            disB[wid] = (dB > 0.f) ? rsqrtf(fmaxf(dB, 1e-12f)) : 0.f;
        }
    }
}

// ---------------- dense matmul h = xin @ W, split in/out ----------------
// one wave computes 4 rows; inA/inB are the two 64-feature halves (strideIn floats/row)
__global__ __launch_bounds__(256) void mm_kernel(const float* __restrict__ inA,
                                                 const float* __restrict__ inB,
                                                 int strideIn,
                                                 const float* __restrict__ W,
                                                 float* __restrict__ hA,
                                                 float* __restrict__ hB, int n) {
    int wid = (blockIdx.x * blockDim.x + threadIdx.x) >> 6;
    int lane = threadIdx.x & 63;
    int i0 = wid * 4;
    if (i0 >= n) return;
    float v0[4], v1[4];
#pragma unroll
    for (int r = 0; r < 4; ++r) {
        int i = i0 + r;
        if (i < n) {
            v0[r] = inA[(size_t)i * strideIn + lane];
            v1[r] = inB[(size_t)i * strideIn + lane];
        } else {
            v0[r] = 0.f; v1[r] = 0.f;
        }
    }
    float acc0[4] = {0.f, 0.f, 0.f, 0.f};
    float acc1[4] = {0.f, 0.f, 0.f, 0.f};
#pragma unroll 4
    for (int k = 0; k < 64; ++k) {
        float w0 = W[k * DF + lane];
        float w1 = W[k * DF + 64 + lane];
#pragma unroll
        for (int r = 0; r < 4; ++r) {
            float a = __shfl(v0[r], k);
            acc0[r] = fmaf(a, w0, acc0[r]);
            acc1[r] = fmaf(a, w1, acc1[r]);
        }
    }
#pragma unroll 4
    for (int k = 0; k < 64; ++k) {
        float w0 = W[(k + 64) * DF + lane];
        float w1 = W[(k + 64) * DF + 64 + lane];
#pragma unroll
        for (int r = 0; r < 4; ++r) {
            float a = __shfl(v1[r], k);
            acc0[r] = fmaf(a, w0, acc0[r]);
            acc1[r] = fmaf(a, w1, acc1[r]);
        }
    }
#pragma unroll
    for (int r = 0; r < 4; ++r) {
        int i = i0 + r;
        if (i < n) {
            hA[(size_t)i * 64 + lane] = acc0[r];
            hB[(size_t)i * 64 + lane] = acc1[r];
        }
    }
}

// ---------------- fused dual SpMM, one feature half (layer 1, relu) ----------------
// lane owns one feature of the half
__global__ __launch_bounds__(256) void spmm_dual_half(const float* __restrict__ hH,
                                                      const float* __restrict__ wsA,
                                                      const float* __restrict__ wsB,
                                                      const int* __restrict__ col_s,
                                                      const float* __restrict__ disA,
                                                      const float* __restrict__ disB,
                                                      const int* __restrict__ row_ptr,
                                                      const float* __restrict__ biasH,
                                                      float* __restrict__ x1H,
                                                      float* __restrict__ x2H,
                                                      const float* __restrict__ sq1in,
                                                      const float* __restrict__ sq2in,
                                                      float* __restrict__ sq1out,
                                                      float* __restrict__ sq2out,
                                                      int finalize, int n) {
    int wid = (blockIdx.x * blockDim.x + threadIdx.x) >> 6;
    int lane = threadIdx.x & 63;
    if (wid >= n) return;
    float diA = disA[wid], diB = disB[wid];
    float hv = hH[(size_t)wid * 64 + lane];
    float aA = diA * hv, aB = diB * hv;
    int s = row_ptr[wid], en = row_ptr[wid + 1];
    for (int base = s; base < en; base += 64) {
        int m = en - base;
        if (m > 64) m = 64;
        int c = 0;
        float ceA = 0.f, ceB = 0.f;
        if (lane < m) {
            c = col_s[base + lane];
            ceA = wsA[base + lane] * disA[c];
            ceB = wsB[base + lane] * disB[c];
        }
        for (int j = 0; j < m; ++j) {
            int cj = __shfl(c, j);
            float cAj = __shfl(ceA, j);
            float cBj = __shfl(ceB, j);
            float g = hH[(size_t)cj * 64 + lane];
            aA = fmaf(cAj, g, aA);
            aB = fmaf(cBj, g, aB);
        }
    }
    float bb = biasH[lane];
    float oA = fmaxf(diA * aA + bb, 0.f);
    float oB = fmaxf(diB * aB + bb, 0.f);
    x1H[(size_t)wid * 64 + lane] = oA;
    x2H[(size_t)wid * 64 + lane] = oB;
    float sA = oA * oA, sB = oB * oB;
    for (int off = 32; off; off >>= 1) {
        sA += __shfl_xor(sA, off);
        sB += __shfl_xor(sB, off);
    }
    if (lane == 0) {
        float pA = finalize ? sq1in[wid] : 0.f;
        float pB = finalize ? sq2in[wid] : 0.f;
        sq1out[wid] = pA + sA;
        sq2out[wid] = pB + sB;
    }
}

// ---------------- single SpMM, one feature half (layer 2, no relu) ----------------
__global__ __launch_bounds__(256) void spmm_half(const float* __restrict__ hH,
                                                 const float* __restrict__ ws,
                                                 const int* __restrict__ col_s,
                                                 const float* __restrict__ dis,
                                                 const int* __restrict__ row_ptr,
                                                 const float* __restrict__ biasH,
                                                 float* __restrict__ xoutH, int n) {
    int wid = (blockIdx.x * blockDim.x + threadIdx.x) >> 6;
    int lane = threadIdx.x & 63;
    if (wid >= n) return;
    float di = dis[wid];
    float hv = hH[(size_t)wid * 64 + lane];
    float a = di * hv;
    int s = row_ptr[wid], en = row_ptr[wid + 1];
    for (int base = s; base < en; base += 64) {
        int m = en - base;
        if (m > 64) m = 64;
        int c = 0;
        float ce = 0.f;
        if (lane < m) {
            c = col_s[base + lane];
            ce = ws[base + lane] * dis[c];
        }
        for (int j = 0; j < m; ++j) {
            int cj = __shfl(c, j);
            float cej = __shfl(ce, j);
            float g = hH[(size_t)cj * 64 + lane];
            a = fmaf(cej, g, a);
        }
    }
    xoutH[(size_t)wid * 64 + lane] = di * a + biasH[lane];
}

// ---------------- semantic attention fusion (split inputs) ----------------
__global__ __launch_bounds__(256) void attn_kernel(const float* __restrict__ x1A,
                                                   const float* __restrict__ x1B,
                                                   const float* __restrict__ x2A,
                                                   const float* __restrict__ x2B,
                                                   const float* __restrict__ A1,
                                                   const float* __restrict__ ab1,
                                                   const float* __restrict__ A2,
                                                   float* __restrict__ out, int n) {
    __shared__ float sA1[DF * HATT];
    __shared__ float sA2[HATT];
    __shared__ float sab[HATT];
    int tid = threadIdx.x;
    for (int i = tid; i < DF * HATT; i += 256) sA1[i] = A1[i];
    if (tid < HATT) {
        sA2[tid] = A2[tid];
        sab[tid] = ab1[tid];
    }
    __syncthreads();
    int lane = tid & 63;
    int wib = tid >> 6;
    int wid = blockIdx.x * 4 + wib;
    int nw = gridDim.x * 4;
    for (int i = wid; i < n; i += nw) {
        float u0 = x1A[(size_t)i * 64 + lane], u1 = x1B[(size_t)i * 64 + lane];
        float v0 = x2A[(size_t)i * 64 + lane], v1 = x2B[(size_t)i * 64 + lane];
        float acc1 = 0.f, acc2 = 0.f;  // lane = hidden unit h
#pragma unroll 4
        for (int d = 0; d < 64; ++d) {
            float w = sA1[d * HATT + lane];
            acc1 = fmaf(__shfl(u0, d), w, acc1);
            acc2 = fmaf(__shfl(v0, d), w, acc2);
        }
#pragma unroll 4
        for (int d = 0; d < 64; ++d) {
            float w = sA1[(d + 64) * HATT + lane];
            acc1 = fmaf(__shfl(u1, d), w, acc1);
            acc2 = fmaf(__shfl(v1, d), w, acc2);
        }
        float t1 = tanhf(acc1 + sab[lane]) * sA2[lane];
        float t2 = tanhf(acc2 + sab[lane]) * sA2[lane];
        for (int off = 32; off; off >>= 1) {
            t1 += __shfl_xor(t1, off);
            t2 += __shfl_xor(t2, off);
        }
        float mx = fmaxf(t1, t2);
        float e1 = expf(t1 - mx), e2 = expf(t2 - mx);
        float inv = 1.f / (e1 + e2);
        float be1 = e1 * inv, be2 = e2 * inv;
        out[(size_t)i * DF + lane] = be1 * u0 + be2 * v0;
        out[(size_t)i * DF + 64 + lane] = be1 * u1 + be2 * v1;
    }
}

// ---------------- launch ----------------

extern "C" void kernel_launch(void* const* d_in, const int* in_sizes, int n_in,
                              void* d_out, int out_size, void* d_ws, size_t ws_size,
                              hipStream_t stream) {
    const float* x  = (const float*)d_in[0];
    const int* row  = (const int*)d_in[1];
    const int* col  = (const int*)d_in[2];
    const float* W1 = (const float*)d_in[3];
    const float* b1 = (const float*)d_in[4];
    const float* W2 = (const float*)d_in[5];
    const float* b2 = (const float*)d_in[6];
    const float* A1 = (const float*)d_in[7];
    const float* ab1= (const float*)d_in[8];
    const float* A2 = (const float*)d_in[9];
    const int N = in_sizes[0] / DF;
    const int E = in_sizes[1];
    float* out = (float*)d_out;

    // workspace layout (~31 MB)
    char* p = (char*)d_ws;
    auto alloc_b = [&](size_t bytes) -> char* {
        char* r = p;
        p += (bytes + 255) & ~(size_t)255;
        return r;
    };
    float* xA   = (float*)alloc_b((size_t)N * 64 * 4);
    float* xB   = (float*)alloc_b((size_t)N * 64 * 4);
    float* hA   = (float*)alloc_b((size_t)N * 64 * 4);
    float* hB   = (float*)alloc_b((size_t)N * 64 * 4);
    float* x1A  = (float*)alloc_b((size_t)N * 64 * 4);
    float* x1B  = (float*)alloc_b((size_t)N * 64 * 4);
    float* x2A  = (float*)alloc_b((size_t)N * 64 * 4);
    float* x2B  = (float*)alloc_b((size_t)N * 64 * 4);
    float* wsA  = (float*)alloc_b((size_t)E * 4);
    float* wsB  = (float*)alloc_b((size_t)E * 4);
    float* dpart= (float*)alloc_b((size_t)E * 4);
    float* disA = (float*)alloc_b((size_t)N * 4);
    float* disB = (float*)alloc_b((size_t)N * 4);
    float* sqnx = (float*)alloc_b((size_t)N * 4);
    float* sqn1 = (float*)alloc_b((size_t)N * 4);
    float* sqn2 = (float*)alloc_b((size_t)N * 4);
    float* sq1p = (float*)alloc_b((size_t)N * 4);
    float* sq2p = (float*)alloc_b((size_t)N * 4);
    int* cnt    = (int*)alloc_b((size_t)N * 4);
    int* cur    = (int*)alloc_b((size_t)N * 4);
    int* rowptr = (int*)alloc_b((size_t)(N + 1) * 4);
    int* col_s  = (int*)alloc_b((size_t)E * 4);
    (void)ws_size; (void)n_in; (void)out_size;

    const int nodeBlocks = divup(N * 64, 256);      // wave per node
    const int mmBlocks   = divup(divup(N, 4), 4);   // wave per 4 rows

    // graph prep
    hipMemsetAsync(cnt, 0, (size_t)N * 4, stream);
    hist_kernel<<<1024, 256, 0, stream>>>(row, cnt, E);
    split_x_kernel<<<nodeBlocks, 256, 0, stream>>>(x, xA, xB, sqnx, N);
    scan_kernel<<<1, 1024, 0, stream>>>(cnt, rowptr, cur, N);
    scatter_kernel<<<1024, 256, 0, stream>>>(row, col, cur, col_s, E);

    // shared layer-1 transform (x in normal layout: halves at x, x+64, stride 128)
    mm_kernel<<<mmBlocks, 256, 0, stream>>>(x, x + 64, DF, W1, hA, hB, N);

    // layer-1 edge weights (cos+euc share the dot), 2-phase, fused deg
    edgewA_kernel<<<nodeBlocks, 256, 0, stream>>>(xA, col_s, rowptr, dpart, N);
    edgewB_kernel<0><<<nodeBlocks, 256, 0, stream>>>(xB, sqnx, col_s, rowptr, dpart,
                                                     wsA, wsB, disA, disB, N);

    // fused dual SpMM layer 1, per feature half
    spmm_dual_half<<<nodeBlocks, 256, 0, stream>>>(hA, wsA, wsB, col_s, disA, disB, rowptr,
                                                   b1, x1A, x2A, sq1p, sq2p, sq1p, sq2p, 0, N);
    spmm_dual_half<<<nodeBlocks, 256, 0, stream>>>(hB, wsA, wsB, col_s, disA, disB, rowptr,
                                                   b1 + 64, x1B, x2B, sq1p, sq2p, sqn1, sqn2, 1, N);

    // layer-2 edge weights: cosine branch on x1
    edgewA_kernel<<<nodeBlocks, 256, 0, stream>>>(x1A, col_s, rowptr, dpart, N);
    edgewB_kernel<1><<<nodeBlocks, 256, 0, stream>>>(x1B, sqn1, col_s, rowptr, dpart,
                                                     wsA, nullptr, disA, nullptr, N);
    // euclid branch on x2
    edgewA_kernel<<<nodeBlocks, 256, 0, stream>>>(x2A, col_s, rowptr, dpart, N);
    edgewB_kernel<2><<<nodeBlocks, 256, 0, stream>>>(x2B, sqn2, col_s, rowptr, dpart,
                                                     wsB, nullptr, disB, nullptr, N);

    // cosine branch layer 2 (overwrite x1A/x1B after mm consumed them)
    mm_kernel<<<mmBlocks, 256, 0, stream>>>(x1A, x1B, 64, W2, hA, hB, N);
    spmm_half<<<nodeBlocks, 256, 0, stream>>>(hA, wsA, col_s, disA, rowptr, b2, x1A, N);
    spmm_half<<<nodeBlocks, 256, 0, stream>>>(hB, wsA, col_s, disA, rowptr, b2 + 64, x1B, N);

    // euclid branch layer 2
    mm_kernel<<<mmBlocks, 256, 0, stream>>>(x2A, x2B, 64, W2, hA, hB, N);
    spmm_half<<<nodeBlocks, 256, 0, stream>>>(hA, wsB, col_s, disB, rowptr, b2, x2A, N);
    spmm_half<<<nodeBlocks, 256, 0, stream>>>(hB, wsB, col_s, disB, rowptr, b2 + 64, x2B, N);

    // semantic attention fusion -> out
    attn_kernel<<<divup(N, 4), 256, 0, stream>>>(x1A, x1B, x2A, x2B, A1, ab1, A2, out, N);
}

// Round 4
// 525.840 us; speedup vs baseline: 1.0943x; 1.0943x over previous
//
#include <hip/hip_runtime.h>
#include <cstdint>
#include <cstddef>

#define DF 128      // feature dim
#define HATT 64     // attention hidden dim

static inline int divup(int a, int b) { return (a + b - 1) / b; }

// ---------------- graph prep ----------------

__global__ __launch_bounds__(256) void hist_kernel(const int* __restrict__ row,
                                                   int* __restrict__ cnt, int E) {
    int i = blockIdx.x * blockDim.x + threadIdx.x;
    int stride = gridDim.x * blockDim.x;
    for (; i < E; i += stride) {
        int r = __builtin_nontemporal_load(row + i);
        atomicAdd(&cnt[r], 1);
    }
}

// single block, 1024 threads: exclusive scan of cnt -> row_ptr, copy to cur
__global__ __launch_bounds__(1024) void scan_kernel(const int* __restrict__ cnt,
                                                    int* __restrict__ row_ptr,
                                                    int* __restrict__ cur, int n) {
    __shared__ int sums[1024];
    int t = threadIdx.x;
    int chunk = (n + 1023) >> 10;
    int start = t * chunk;
    int s = 0;
    for (int j = 0; j < chunk; ++j) {
        int idx = start + j;
        if (idx < n) s += cnt[idx];
    }
    sums[t] = s;
    __syncthreads();
    for (int off = 1; off < 1024; off <<= 1) {
        int v = (t >= off) ? sums[t - off] : 0;
        __syncthreads();
        sums[t] += v;
        __syncthreads();
    }
    int run = sums[t] - s;  // exclusive prefix
    for (int j = 0; j < chunk; ++j) {
        int idx = start + j;
        if (idx < n) {
            row_ptr[idx] = run;
            cur[idx] = run;
            run += cnt[idx];
        }
    }
    if (t == 1023) row_ptr[n] = sums[1023];
}

__global__ __launch_bounds__(256) void scatter_kernel(const int* __restrict__ row,
                                                      const int* __restrict__ col,
                                                      int* __restrict__ cur,
                                                      unsigned short* __restrict__ col_s, int E) {
    int i = blockIdx.x * blockDim.x + threadIdx.x;
    int stride = gridDim.x * blockDim.x;
    for (; i < E; i += stride) {
        int r = __builtin_nontemporal_load(row + i);
        int c = __builtin_nontemporal_load(col + i);
        int p = atomicAdd(&cur[r], 1);
        col_s[p] = (unsigned short)c;
    }
}

// ---------------- split x into two 64-feature halves + squared norms ----------------

__global__ __launch_bounds__(256) void split_x_kernel(const float* __restrict__ x,
                                                      float* __restrict__ xA,
                                                      float* __restrict__ xB,
                                                      float* __restrict__ sqn, int n) {
    int wid = (blockIdx.x * blockDim.x + threadIdx.x) >> 6;
    int lane = threadIdx.x & 63;
    if (wid >= n) return;
    float v0 = x[(size_t)wid * DF + lane];
    float v1 = x[(size_t)wid * DF + 64 + lane];
    xA[(size_t)wid * 64 + lane] = v0;
    xB[(size_t)wid * 64 + lane] = v1;
    float s = v0 * v0 + v1 * v1;
    for (int off = 32; off; off >>= 1) s += __shfl_xor(s, off);
    if (lane == 0) sqn[wid] = s;
}

// ---------------- edge weights, 2-phase over feature halves ----------------
// pass A: partial dot over half-table tA (2.56 MB, L2-resident) -> dpart[E]
__global__ __launch_bounds__(256) void edgewA_kernel(const float* __restrict__ tA,
                                                     const unsigned short* __restrict__ col_s,
                                                     const int* __restrict__ row_ptr,
                                                     float* __restrict__ dpart, int n) {
    int wid = (blockIdx.x * blockDim.x + threadIdx.x) >> 6;
    int lane = threadIdx.x & 63;
    if (wid >= n) return;
    int sub = lane & 15;   // 16 lanes per edge
    int g = lane >> 4;     // 4 edge groups per wave
    int s = row_ptr[wid], e = row_ptr[wid + 1];
    float4 a = ((const float4*)(tA + (size_t)wid * 64))[sub];
#pragma unroll 2
    for (int p = s + g; p < e; p += 4) {
        int c = (int)col_s[p];
        float4 b = ((const float4*)(tA + (size_t)c * 64))[sub];
        float d = a.x * b.x + a.y * b.y + a.z * b.z + a.w * b.w;
        for (int off = 8; off; off >>= 1) d += __shfl_xor(d, off);
        if (sub == 0) dpart[p] = d;
    }
}

// pass B: finish dot with half-table tB, emit weights, fused degree -> dis
// METRIC: 0 = both (wA=cos->disA, wB=euc->disB), 1 = cos only, 2 = euc only
template <int METRIC>
__global__ __launch_bounds__(256) void edgewB_kernel(const float* __restrict__ tB,
                                                     const float* __restrict__ sqn,
                                                     const unsigned short* __restrict__ col_s,
                                                     const int* __restrict__ row_ptr,
                                                     const float* __restrict__ dpart,
                                                     float* __restrict__ wA,
                                                     float* __restrict__ wB,
                                                     float* __restrict__ disA,
                                                     float* __restrict__ disB, int n) {
    int wid = (blockIdx.x * blockDim.x + threadIdx.x) >> 6;
    int lane = threadIdx.x & 63;
    if (wid >= n) return;
    int sub = lane & 15;
    int g = lane >> 4;
    int s = row_ptr[wid], e = row_ptr[wid + 1];
    float4 a = ((const float4*)(tB + (size_t)wid * 64))[sub];
    float na = sqn[wid];
    float accA = 0.f, accB = 0.f;
#pragma unroll 2
    for (int p = s + g; p < e; p += 4) {
        int c = (int)col_s[p];
        float4 b = ((const float4*)(tB + (size_t)c * 64))[sub];
        float d = a.x * b.x + a.y * b.y + a.z * b.z + a.w * b.w;
        for (int off = 8; off; off >>= 1) d += __shfl_xor(d, off);
        if (sub == 0) {
            d += __builtin_nontemporal_load(dpart + p);
            float nb = sqn[c];
            if (METRIC != 2) {
                float cw = d / fmaxf(sqrtf(na * nb), 1e-8f);
                wA[p] = cw;
                accA += cw;
            }
            if (METRIC == 0) {
                float ew = sqrtf(fmaxf(na + nb - 2.f * d, 0.f) + 1e-12f);
                wB[p] = ew;
                accB += ew;
            }
            if (METRIC == 2) {
                float ew = sqrtf(fmaxf(na + nb - 2.f * d, 0.f) + 1e-12f);
                wA[p] = ew;
                accA += ew;
            }
        }
    }
    // group sums live on lanes 0,16,32,48; fold them into lane 0
    accA += __shfl_xor(accA, 32);
    accA += __shfl_xor(accA, 16);
    if (METRIC == 0) {
        accB += __shfl_xor(accB, 32);
        accB += __shfl_xor(accB, 16);
    }
    if (lane == 0) {
        float dA = 1.f + accA;
        disA[wid] = (dA > 0.f) ? rsqrtf(fmaxf(dA, 1e-12f)) : 0.f;
        if (METRIC == 0) {
            float dB = 1.f + accB;
            disB[wid] = (dB > 0.f) ? rsqrtf(fmaxf(dB, 1e-12f)) : 0.f;
        }
    }
}

// ---------------- dense matmul h = xin @ W, split in/out ----------------
// one wave computes 4 rows; inA/inB are the two 64-feature halves (strideIn floats/row)
__global__ __launch_bounds__(256) void mm_kernel(const float* __restrict__ inA,
                                                 const float* __restrict__ inB,
                                                 int strideIn,
                                                 const float* __restrict__ W,
                                                 float* __restrict__ hA,
                                                 float* __restrict__ hB, int n) {
    int wid = (blockIdx.x * blockDim.x + threadIdx.x) >> 6;
    int lane = threadIdx.x & 63;
    int i0 = wid * 4;
    if (i0 >= n) return;
    float v0[4], v1[4];
#pragma unroll
    for (int r = 0; r < 4; ++r) {
        int i = i0 + r;
        if (i < n) {
            v0[r] = inA[(size_t)i * strideIn + lane];
            v1[r] = inB[(size_t)i * strideIn + lane];
        } else {
            v0[r] = 0.f; v1[r] = 0.f;
        }
    }
    float acc0[4] = {0.f, 0.f, 0.f, 0.f};
    float acc1[4] = {0.f, 0.f, 0.f, 0.f};
#pragma unroll 4
    for (int k = 0; k < 64; ++k) {
        float w0 = W[k * DF + lane];
        float w1 = W[k * DF + 64 + lane];
#pragma unroll
        for (int r = 0; r < 4; ++r) {
            float a = __shfl(v0[r], k);
            acc0[r] = fmaf(a, w0, acc0[r]);
            acc1[r] = fmaf(a, w1, acc1[r]);
        }
    }
#pragma unroll 4
    for (int k = 0; k < 64; ++k) {
        float w0 = W[(k + 64) * DF + lane];
        float w1 = W[(k + 64) * DF + 64 + lane];
#pragma unroll
        for (int r = 0; r < 4; ++r) {
            float a = __shfl(v1[r], k);
            acc0[r] = fmaf(a, w0, acc0[r]);
            acc1[r] = fmaf(a, w1, acc1[r]);
        }
    }
#pragma unroll
    for (int r = 0; r < 4; ++r) {
        int i = i0 + r;
        if (i < n) {
            hA[(size_t)i * 64 + lane] = acc0[r];
            hB[(size_t)i * 64 + lane] = acc1[r];
        }
    }
}

// ---------------- fused dual SpMM, one feature half (layer 1, relu) ----------------
// 16 lanes per edge, 4 edge groups per wave; float4 accumulators; cross-group reduce.
__global__ __launch_bounds__(256) void spmm_dual_half(const float* __restrict__ hH,
                                                      const float* __restrict__ wsA,
                                                      const float* __restrict__ wsB,
                                                      const unsigned short* __restrict__ col_s,
                                                      const float* __restrict__ disA,
                                                      const float* __restrict__ disB,
                                                      const int* __restrict__ row_ptr,
                                                      const float* __restrict__ biasH,
                                                      float* __restrict__ x1H,
                                                      float* __restrict__ x2H,
                                                      const float* __restrict__ sq1in,
                                                      const float* __restrict__ sq2in,
                                                      float* __restrict__ sq1out,
                                                      float* __restrict__ sq2out,
                                                      int finalize, int n) {
    int wid = (blockIdx.x * blockDim.x + threadIdx.x) >> 6;
    int lane = threadIdx.x & 63;
    if (wid >= n) return;
    int sub = lane & 15;
    int g = lane >> 4;
    int s = row_ptr[wid], e = row_ptr[wid + 1];
    float diA = disA[wid], diB = disB[wid];
    float4 aA = make_float4(0.f, 0.f, 0.f, 0.f);
    float4 aB = make_float4(0.f, 0.f, 0.f, 0.f);
#pragma unroll 2
    for (int p = s + g; p < e; p += 4) {
        int c = (int)col_s[p];
        float wAe = __builtin_nontemporal_load(wsA + p);
        float wBe = __builtin_nontemporal_load(wsB + p);
        float ceA = wAe * disA[c];
        float ceB = wBe * disB[c];
        float4 gv = ((const float4*)(hH + (size_t)c * 64))[sub];
        aA.x = fmaf(ceA, gv.x, aA.x);
        aA.y = fmaf(ceA, gv.y, aA.y);
        aA.z = fmaf(ceA, gv.z, aA.z);
        aA.w = fmaf(ceA, gv.w, aA.w);
        aB.x = fmaf(ceB, gv.x, aB.x);
        aB.y = fmaf(ceB, gv.y, aB.y);
        aB.z = fmaf(ceB, gv.z, aB.z);
        aB.w = fmaf(ceB, gv.w, aB.w);
    }
    // cross-group reduce (groups hold partials for the same features)
#pragma unroll
    for (int off = 16; off <= 32; off <<= 1) {
        aA.x += __shfl_xor(aA.x, off);
        aA.y += __shfl_xor(aA.y, off);
        aA.z += __shfl_xor(aA.z, off);
        aA.w += __shfl_xor(aA.w, off);
        aB.x += __shfl_xor(aB.x, off);
        aB.y += __shfl_xor(aB.y, off);
        aB.z += __shfl_xor(aB.z, off);
        aB.w += __shfl_xor(aB.w, off);
    }
    float4 hv = ((const float4*)(hH + (size_t)wid * 64))[sub];
    float4 bb = ((const float4*)biasH)[sub];
    float4 oA, oB;
    oA.x = fmaxf(diA * (aA.x + diA * hv.x) + bb.x, 0.f);
    oA.y = fmaxf(diA * (aA.y + diA * hv.y) + bb.y, 0.f);
    oA.z = fmaxf(diA * (aA.z + diA * hv.z) + bb.z, 0.f);
    oA.w = fmaxf(diA * (aA.w + diA * hv.w) + bb.w, 0.f);
    oB.x = fmaxf(diB * (aB.x + diB * hv.x) + bb.x, 0.f);
    oB.y = fmaxf(diB * (aB.y + diB * hv.y) + bb.y, 0.f);
    oB.z = fmaxf(diB * (aB.z + diB * hv.z) + bb.z, 0.f);
    oB.w = fmaxf(diB * (aB.w + diB * hv.w) + bb.w, 0.f);
    if (g == 0) {
        ((float4*)(x1H + (size_t)wid * 64))[sub] = oA;
        ((float4*)(x2H + (size_t)wid * 64))[sub] = oB;
    }
    // half-norms: features live on sub 0..15 (groups duplicate) -> reduce over sub
    float sA = oA.x * oA.x + oA.y * oA.y + oA.z * oA.z + oA.w * oA.w;
    float sB = oB.x * oB.x + oB.y * oB.y + oB.z * oB.z + oB.w * oB.w;
#pragma unroll
    for (int off = 8; off; off >>= 1) {
        sA += __shfl_xor(sA, off);
        sB += __shfl_xor(sB, off);
    }
    if (lane == 0) {
        float pA = finalize ? sq1in[wid] : 0.f;
        float pB = finalize ? sq2in[wid] : 0.f;
        sq1out[wid] = pA + sA;
        sq2out[wid] = pB + sB;
    }
}

// ---------------- single SpMM, one feature half (layer 2, no relu) ----------------
__global__ __launch_bounds__(256) void spmm_half(const float* __restrict__ hH,
                                                 const float* __restrict__ ws,
                                                 const unsigned short* __restrict__ col_s,
                                                 const float* __restrict__ dis,
                                                 const int* __restrict__ row_ptr,
                                                 const float* __restrict__ biasH,
                                                 float* __restrict__ xoutH, int n) {
    int wid = (blockIdx.x * blockDim.x + threadIdx.x) >> 6;
    int lane = threadIdx.x & 63;
    if (wid >= n) return;
    int sub = lane & 15;
    int g = lane >> 4;
    int s = row_ptr[wid], e = row_ptr[wid + 1];
    float di = dis[wid];
    float4 a = make_float4(0.f, 0.f, 0.f, 0.f);
#pragma unroll 2
    for (int p = s + g; p < e; p += 4) {
        int c = (int)col_s[p];
        float we = __builtin_nontemporal_load(ws + p);
        float ce = we * dis[c];
        float4 gv = ((const float4*)(hH + (size_t)c * 64))[sub];
        a.x = fmaf(ce, gv.x, a.x);
        a.y = fmaf(ce, gv.y, a.y);
        a.z = fmaf(ce, gv.z, a.z);
        a.w = fmaf(ce, gv.w, a.w);
    }
#pragma unroll
    for (int off = 16; off <= 32; off <<= 1) {
        a.x += __shfl_xor(a.x, off);
        a.y += __shfl_xor(a.y, off);
        a.z += __shfl_xor(a.z, off);
        a.w += __shfl_xor(a.w, off);
    }
    if (g == 0) {
        float4 hv = ((const float4*)(hH + (size_t)wid * 64))[sub];
        float4 bb = ((const float4*)biasH)[sub];
        float4 o;
        o.x = di * (a.x + di * hv.x) + bb.x;
        o.y = di * (a.y + di * hv.y) + bb.y;
        o.z = di * (a.z + di * hv.z) + bb.z;
        o.w = di * (a.w + di * hv.w) + bb.w;
        ((float4*)(xoutH + (size_t)wid * 64))[sub] = o;
    }
}

// ---------------- semantic attention fusion (split inputs) ----------------
__global__ __launch_bounds__(256) void attn_kernel(const float* __restrict__ x1A,
                                                   const float* __restrict__ x1B,
                                                   const float* __restrict__ x2A,
                                                   const float* __restrict__ x2B,
                                                   const float* __restrict__ A1,
                                                   const float* __restrict__ ab1,
                                                   const float* __restrict__ A2,
                                                   float* __restrict__ out, int n) {
    __shared__ float sA1[DF * HATT];
    __shared__ float sA2[HATT];
    __shared__ float sab[HATT];
    int tid = threadIdx.x;
    for (int i = tid; i < DF * HATT; i += 256) sA1[i] = A1[i];
    if (tid < HATT) {
        sA2[tid] = A2[tid];
        sab[tid] = ab1[tid];
    }
    __syncthreads();
    int lane = tid & 63;
    int wib = tid >> 6;
    int wid = blockIdx.x * 4 + wib;
    int nw = gridDim.x * 4;
    for (int i = wid; i < n; i += nw) {
        float u0 = x1A[(size_t)i * 64 + lane], u1 = x1B[(size_t)i * 64 + lane];
        float v0 = x2A[(size_t)i * 64 + lane], v1 = x2B[(size_t)i * 64 + lane];
        float acc1 = 0.f, acc2 = 0.f;  // lane = hidden unit h
#pragma unroll 4
        for (int d = 0; d < 64; ++d) {
            float w = sA1[d * HATT + lane];
            acc1 = fmaf(__shfl(u0, d), w, acc1);
            acc2 = fmaf(__shfl(v0, d), w, acc2);
        }
#pragma unroll 4
        for (int d = 0; d < 64; ++d) {
            float w = sA1[(d + 64) * HATT + lane];
            acc1 = fmaf(__shfl(u1, d), w, acc1);
            acc2 = fmaf(__shfl(v1, d), w, acc2);
        }
        float t1 = tanhf(acc1 + sab[lane]) * sA2[lane];
        float t2 = tanhf(acc2 + sab[lane]) * sA2[lane];
        for (int off = 32; off; off >>= 1) {
            t1 += __shfl_xor(t1, off);
            t2 += __shfl_xor(t2, off);
        }
        float mx = fmaxf(t1, t2);
        float e1 = expf(t1 - mx), e2 = expf(t2 - mx);
        float inv = 1.f / (e1 + e2);
        float be1 = e1 * inv, be2 = e2 * inv;
        out[(size_t)i * DF + lane] = be1 * u0 + be2 * v0;
        out[(size_t)i * DF + 64 + lane] = be1 * u1 + be2 * v1;
    }
}

// ---------------- launch ----------------

extern "C" void kernel_launch(void* const* d_in, const int* in_sizes, int n_in,
                              void* d_out, int out_size, void* d_ws, size_t ws_size,
                              hipStream_t stream) {
    const float* x  = (const float*)d_in[0];
    const int* row  = (const int*)d_in[1];
    const int* col  = (const int*)d_in[2];
    const float* W1 = (const float*)d_in[3];
    const float* b1 = (const float*)d_in[4];
    const float* W2 = (const float*)d_in[5];
    const float* b2 = (const float*)d_in[6];
    const float* A1 = (const float*)d_in[7];
    const float* ab1= (const float*)d_in[8];
    const float* A2 = (const float*)d_in[9];
    const int N = in_sizes[0] / DF;
    const int E = in_sizes[1];
    float* out = (float*)d_out;

    // workspace layout (~30 MB)
    char* p = (char*)d_ws;
    auto alloc_b = [&](size_t bytes) -> char* {
        char* r = p;
        p += (bytes + 255) & ~(size_t)255;
        return r;
    };
    float* xA   = (float*)alloc_b((size_t)N * 64 * 4);
    float* xB   = (float*)alloc_b((size_t)N * 64 * 4);
    float* hA   = (float*)alloc_b((size_t)N * 64 * 4);
    float* hB   = (float*)alloc_b((size_t)N * 64 * 4);
    float* x1A  = (float*)alloc_b((size_t)N * 64 * 4);
    float* x1B  = (float*)alloc_b((size_t)N * 64 * 4);
    float* x2A  = (float*)alloc_b((size_t)N * 64 * 4);
    float* x2B  = (float*)alloc_b((size_t)N * 64 * 4);
    float* wsA  = (float*)alloc_b((size_t)E * 4);
    float* wsB  = (float*)alloc_b((size_t)E * 4);
    float* dpart= (float*)alloc_b((size_t)E * 4);
    float* disA = (float*)alloc_b((size_t)N * 4);
    float* disB = (float*)alloc_b((size_t)N * 4);
    float* sqnx = (float*)alloc_b((size_t)N * 4);
    float* sqn1 = (float*)alloc_b((size_t)N * 4);
    float* sqn2 = (float*)alloc_b((size_t)N * 4);
    float* sq1p = (float*)alloc_b((size_t)N * 4);
    float* sq2p = (float*)alloc_b((size_t)N * 4);
    int* cnt    = (int*)alloc_b((size_t)N * 4);
    int* cur    = (int*)alloc_b((size_t)N * 4);
    int* rowptr = (int*)alloc_b((size_t)(N + 1) * 4);
    unsigned short* col_s = (unsigned short*)alloc_b((size_t)E * 2);
    (void)ws_size; (void)n_in; (void)out_size;

    const int nodeBlocks = divup(N * 64, 256);      // wave per node
    const int mmBlocks   = divup(divup(N, 4), 4);   // wave per 4 rows

    // graph prep
    hipMemsetAsync(cnt, 0, (size_t)N * 4, stream);
    hist_kernel<<<1024, 256, 0, stream>>>(row, cnt, E);
    split_x_kernel<<<nodeBlocks, 256, 0, stream>>>(x, xA, xB, sqnx, N);
    scan_kernel<<<1, 1024, 0, stream>>>(cnt, rowptr, cur, N);
    scatter_kernel<<<1024, 256, 0, stream>>>(row, col, cur, col_s, E);

    // shared layer-1 transform (x in normal layout: halves at x, x+64, stride 128)
    mm_kernel<<<mmBlocks, 256, 0, stream>>>(x, x + 64, DF, W1, hA, hB, N);

    // layer-1 edge weights (cos+euc share the dot), 2-phase, fused deg
    edgewA_kernel<<<nodeBlocks, 256, 0, stream>>>(xA, col_s, rowptr, dpart, N);
    edgewB_kernel<0><<<nodeBlocks, 256, 0, stream>>>(xB, sqnx, col_s, rowptr, dpart,
                                                     wsA, wsB, disA, disB, N);

    // fused dual SpMM layer 1, per feature half
    spmm_dual_half<<<nodeBlocks, 256, 0, stream>>>(hA, wsA, wsB, col_s, disA, disB, rowptr,
                                                   b1, x1A, x2A, sq1p, sq2p, sq1p, sq2p, 0, N);
    spmm_dual_half<<<nodeBlocks, 256, 0, stream>>>(hB, wsA, wsB, col_s, disA, disB, rowptr,
                                                   b1 + 64, x1B, x2B, sq1p, sq2p, sqn1, sqn2, 1, N);

    // layer-2 edge weights: cosine branch on x1
    edgewA_kernel<<<nodeBlocks, 256, 0, stream>>>(x1A, col_s, rowptr, dpart, N);
    edgewB_kernel<1><<<nodeBlocks, 256, 0, stream>>>(x1B, sqn1, col_s, rowptr, dpart,
                                                     wsA, nullptr, disA, nullptr, N);
    // euclid branch on x2
    edgewA_kernel<<<nodeBlocks, 256, 0, stream>>>(x2A, col_s, rowptr, dpart, N);
    edgewB_kernel<2><<<nodeBlocks, 256, 0, stream>>>(x2B, sqn2, col_s, rowptr, dpart,
                                                     wsB, nullptr, disB, nullptr, N);

    // cosine branch layer 2 (overwrite x1A/x1B after mm consumed them)
    mm_kernel<<<mmBlocks, 256, 0, stream>>>(x1A, x1B, 64, W2, hA, hB, N);
    spmm_half<<<nodeBlocks, 256, 0, stream>>>(hA, wsA, col_s, disA, rowptr, b2, x1A, N);
    spmm_half<<<nodeBlocks, 256, 0, stream>>>(hB, wsA, col_s, disA, rowptr, b2 + 64, x1B, N);

    // euclid branch layer 2
    mm_kernel<<<mmBlocks, 256, 0, stream>>>(x2A, x2B, 64, W2, hA, hB, N);
    spmm_half<<<nodeBlocks, 256, 0, stream>>>(hA, wsB, col_s, disB, rowptr, b2, x2A, N);
    spmm_half<<<nodeBlocks, 256, 0, stream>>>(hB, wsB, col_s, disB, rowptr, b2 + 64, x2B, N);

    // semantic attention fusion -> out
    attn_kernel<<<divup(N, 4), 256, 0, stream>>>(x1A, x1B, x2A, x2B, A1, ab1, A2, out, N);
}